// Round 3
// baseline (651.295 us; speedup 1.0000x reference)
//
#include <hip/hip_runtime.h>

#define NMAX   1024
#define BB     128
#define BINS   64
#define ROWS   32            // rows per chunk; NMAX/ROWS = 32 chunks per batch
#define NCHUNK (NMAX / ROWS)

// Per block: one batch b, 32 consecutive rows, 256 threads, thread t owns
// columns 4t..4t+3 (one float4 per row). adj entries are exactly 0.0 or 1.0:
// row sums are popcounts via __ballot (v_cmp -> SGPR pair, popcount+add on
// the scalar pipe). Column sums accumulate in 4 private registers across the
// 32 rows and are written as per-chunk PARTIALS to a private slice of ws
// (no pre-zeroed accumulator, no global atomics, no memset dispatch).
__global__ __launch_bounds__(256) void degree_kernel(
    const float* __restrict__ adj, const int* __restrict__ num_nodes,
    float* __restrict__ in_deg,            // [BB][NMAX]
    float* __restrict__ colpart)           // [BB][NCHUNK][NMAX]
{
    const int b     = blockIdx.x >> 5;     // 32 chunks per batch
    const int chunk = blockIdx.x & 31;
    const int n     = num_nodes[b];
    const int row0  = chunk * ROWS;
    if (row0 >= n) return;                 // whole chunk masked out; never read

    const int t    = threadIdx.x;
    const int lane = t & 63;
    const int wave = t >> 6;
    const int j0   = t * 4;
    const bool act = (j0 < n);             // thread has at least one valid col

    // fold column validity into the compare threshold: invalid cols never pass
    const float BIG = 3.0e38f;
    const float th0 = (j0 + 0 < n) ? 0.5f : BIG;
    const float th1 = (j0 + 1 < n) ? 0.5f : BIG;
    const float th2 = (j0 + 2 < n) ? 0.5f : BIG;
    const float th3 = (j0 + 3 < n) ? 0.5f : BIG;

    float c0 = 0.f, c1 = 0.f, c2 = 0.f, c3 = 0.f;

    __shared__ float rowpart[ROWS][4];     // [row_in_chunk][wave]

    const int rows = min(ROWS, n - row0);
    const float4* base = (const float4*)(adj + ((size_t)b * NMAX + row0) * NMAX) + t;

    #pragma unroll 8
    for (int r = 0; r < rows; ++r) {
        float4 v = make_float4(0.f, 0.f, 0.f, 0.f);
        if (act) v = base[r * (NMAX / 4)];            // coalesced 16B/lane
        const bool p0 = v.x > th0;
        const bool p1 = v.y > th1;
        const bool p2 = v.z > th2;
        const bool p3 = v.w > th3;
        c0 += p0 ? 1.f : 0.f;
        c1 += p1 ? 1.f : 0.f;
        c2 += p2 ? 1.f : 0.f;
        c3 += p3 ? 1.f : 0.f;
        const unsigned long long b0 = __ballot(p0);
        const unsigned long long b1 = __ballot(p1);
        const unsigned long long b2 = __ballot(p2);
        const unsigned long long b3 = __ballot(p3);
        const int rs = __popcll(b0) + __popcll(b1) + __popcll(b2) + __popcll(b3);
        if (lane == 0) rowpart[r][wave] = (float)rs;  // wave-uniform value
    }
    __syncthreads();

    if (t < rows) {
        const float s = rowpart[t][0] + rowpart[t][1] + rowpart[t][2] + rowpart[t][3];
        in_deg[b * NMAX + row0 + t] = s;   // unique row per block: plain store
    }

    if (act) {                             // cols j >= n are never read downstream
        float4* cp = (float4*)(colpart + (((size_t)b * NCHUNK + chunk) << 10)) + t;
        *cp = make_float4(c0, c1, c2, c3);
    }
}

// One block per (side, b). side 0: histogram of in_deg[b][0..n). side 1: sum
// the ceil(n/32) per-chunk column partials, then histogram. Triangle kernel
// with width = 1/spacing -> each degree touches only bins floor(d/sp) and
// floor(d/sp)+1; score uses the exact reference formula with the input arrays.
__global__ __launch_bounds__(256) void hist_kernel(
    const float* __restrict__ in_deg, const float* __restrict__ colpart,
    const int* __restrict__ num_nodes,
    const float* __restrict__ centers, const float* __restrict__ widths,
    float* __restrict__ out)
{
    const int side = blockIdx.x >> 7;      // 0: in (row sums), 1: out (col sums)
    const int b    = blockIdx.x & 127;

    __shared__ float hist[BINS];
    __shared__ float c[BINS];
    __shared__ float w[BINS];
    if (threadIdx.x < BINS) {
        hist[threadIdx.x] = 0.f;
        c[threadIdx.x] = centers[threadIdx.x];
        w[threadIdx.x] = widths[threadIdx.x];
    }
    __syncthreads();

    const int n = num_nodes[b];
    const int nchunks = (n + ROWS - 1) / ROWS;
    const float inv_sp = w[0];             // 1/spacing (uniform bins)

    for (int i = threadIdx.x; i < n; i += 256) {
        float d;
        if (side == 0) {
            d = in_deg[b * NMAX + i];
        } else {
            d = 0.f;
            const float* cp = colpart + ((size_t)b * NCHUNK << 10) + i;
            for (int ch = 0; ch < nchunks; ++ch)
                d += cp[(size_t)ch << 10];  // coalesced across i per chunk
        }
        const float pos = d * inv_sp;
        const int   k0  = (int)floorf(pos);
        #pragma unroll
        for (int kk = 0; kk < 2; ++kk) {
            const int k = k0 + kk;
            if (k >= 0 && k < BINS) {
                const float s = 1.f - fabsf(d - c[k]) * w[k];
                if (s > 0.f) atomicAdd(&hist[k], s);
            }
        }
    }
    __syncthreads();

    if (threadIdx.x < BINS)
        out[((size_t)side * BB + b) * BINS + threadIdx.x] = hist[threadIdx.x];
}

extern "C" void kernel_launch(void* const* d_in, const int* in_sizes, int n_in,
                              void* d_out, int out_size, void* d_ws, size_t ws_size,
                              hipStream_t stream) {
    const float* adj       = (const float*)d_in[0];
    const int*   num_nodes = (const int*)d_in[1];
    const float* centers   = (const float*)d_in[2];
    const float* widths    = (const float*)d_in[3];
    float* out = (float*)d_out;

    // ws layout: in_deg [BB][NMAX], then colpart [BB][NCHUNK][NMAX].
    // Every location read downstream is written unconditionally upstream,
    // so no zero-initialization (and no fill dispatch) is needed.
    float* in_deg  = (float*)d_ws;
    float* colpart = in_deg + (size_t)BB * NMAX;

    degree_kernel<<<BB * NCHUNK, 256, 0, stream>>>(adj, num_nodes, in_deg, colpart);

    hist_kernel<<<2 * BB, 256, 0, stream>>>(in_deg, colpart, num_nodes,
                                            centers, widths, out);
}